// Round 1
// baseline (2757.126 us; speedup 1.0000x reference)
//
#include <hip/hip_runtime.h>
#include <math.h>

// Problem constants
#define NB    8192          // N
#define FEAT  255
#define HID   64
#define TOPK  6000
#define POSTK 300
#define BINS  8192          // 13-bit sortable-float key bins (sign+8exp+4mant)
#define BSHIFT 19           // 32-13
#define CAP   131072        // candidate buffer capacity
#define SLACK 2             // extra bins below threshold bin (absorbs f32 vs f64 noise)

__device__ __forceinline__ unsigned binOf(float x) {
    unsigned u = __float_as_uint(x);
    u = (u & 0x80000000u) ? ~u : (u | 0x80000000u);   // sortable key (ascending)
    return u >> BSHIFT;
}

// ---------------------------------------------------------------------------
// K1: the two 255->64->64 MLPs in f64. One block = 4 rows, 64 threads/row.
// Writes row-major f64 (for pass B) and transposed f32 [k][n] (for pass A).
// ---------------------------------------------------------------------------
__global__ __launch_bounds__(256) void mlp_kernel(
    const float* __restrict__ feat,
    const float* __restrict__ W1s, const float* __restrict__ b1s,
    const float* __restrict__ W2s, const float* __restrict__ b2s,
    const float* __restrict__ W1o, const float* __restrict__ b1o,
    const float* __restrict__ W2o, const float* __restrict__ b2o,
    double* __restrict__ Xs64, double* __restrict__ Xo64,
    float* __restrict__ XsT, float* __restrict__ XoT)
{
    int tid  = threadIdx.x;
    int trow = tid >> 6;          // 0..3
    int t    = tid & 63;          // hidden unit
    int r    = blockIdx.x * 4 + trow;
    __shared__ double hs[4][64];
    __shared__ double ho[4][64];

    const float* frow = feat + (size_t)r * FEAT;
    double as = (double)b1s[t];
    double ao = (double)b1o[t];
    for (int k = 0; k < FEAT; ++k) {
        double fv = (double)frow[k];
        as += fv * (double)W1s[k * HID + t];
        ao += fv * (double)W1o[k * HID + t];
    }
    hs[trow][t] = as > 0.0 ? as : 0.0;
    ho[trow][t] = ao > 0.0 ? ao : 0.0;
    __syncthreads();

    double xs = (double)b2s[t];
    double xo = (double)b2o[t];
    for (int k = 0; k < HID; ++k) {
        xs += hs[trow][k] * (double)W2s[k * HID + t];
        xo += ho[trow][k] * (double)W2o[k * HID + t];
    }
    size_t o = (size_t)r * HID + t;
    Xs64[o] = xs;
    Xo64[o] = xo;
    XsT[(size_t)t * NB + r] = (float)xs;   // [k][n] layout for coalesced pass A
    XoT[(size_t)t * NB + r] = (float)xo;
}

// ---------------------------------------------------------------------------
// K2: pass A — f32 logits for all 8192^2 pairs. 128x128 tile / block,
// 256 threads x (8x8 micro-tile). Histogram keys in LDS, merge sparse bins.
// Also records per-tile max for pass-B tile skipping.
// ---------------------------------------------------------------------------
__global__ __launch_bounds__(256) void scores_pass_a(
    const float* __restrict__ XsT, const float* __restrict__ XoT,
    unsigned* __restrict__ ghist, float* __restrict__ tmax)
{
    __shared__ unsigned hist[BINS];   // 32 KB
    __shared__ float smax[256];
    int tid = threadIdx.x;
    for (int i = tid; i < BINS; i += 256) hist[i] = 0u;
    __syncthreads();

    int tr = tid >> 4, tc = tid & 15;
    int r0 = blockIdx.y * 128 + tr * 8;
    int c0 = blockIdx.x * 128 + tc * 8;

    float acc[8][8];
#pragma unroll
    for (int i = 0; i < 8; ++i)
#pragma unroll
        for (int j = 0; j < 8; ++j) acc[i][j] = 0.0f;

    for (int k = 0; k < HID; ++k) {
        const float4* ap = (const float4*)(XsT + (size_t)k * NB + r0);
        const float4* bp = (const float4*)(XoT + (size_t)k * NB + c0);
        float4 a0 = ap[0], a1 = ap[1];
        float4 b0 = bp[0], b1 = bp[1];
        float a[8] = {a0.x, a0.y, a0.z, a0.w, a1.x, a1.y, a1.z, a1.w};
        float b[8] = {b0.x, b0.y, b0.z, b0.w, b1.x, b1.y, b1.z, b1.w};
#pragma unroll
        for (int i = 0; i < 8; ++i)
#pragma unroll
            for (int j = 0; j < 8; ++j)
                acc[i][j] = fmaf(a[i], b[j], acc[i][j]);
    }

    float vmax = -3.0e38f;
#pragma unroll
    for (int i = 0; i < 8; ++i)
#pragma unroll
        for (int j = 0; j < 8; ++j) {
            float v = acc[i][j];
            if (r0 + i == c0 + j) v = -1.0f;      // diagonal, like reference
            vmax = fmaxf(vmax, v);
            atomicAdd(&hist[binOf(v)], 1u);
        }

    smax[tid] = vmax;
    __syncthreads();
    for (int st = 128; st > 0; st >>= 1) {
        if (tid < st) smax[tid] = fmaxf(smax[tid], smax[tid + st]);
        __syncthreads();
    }
    if (tid == 0) tmax[blockIdx.y * gridDim.x + blockIdx.x] = smax[0];

    for (int i = tid; i < BINS; i += 256) {
        unsigned h = hist[i];
        if (h) atomicAdd(&ghist[i], h);
    }
}

// ---------------------------------------------------------------------------
// K3: find threshold bin b* (largest b with cnt_ge[b] >= TOPK); write
// ctrl[1] = b* - SLACK (raised if candidate count would exceed CAP).
// ---------------------------------------------------------------------------
__global__ __launch_bounds__(256) void find_threshold(
    const unsigned* __restrict__ ghist, unsigned* __restrict__ ctrl)
{
    __shared__ unsigned csum[256];
    int tid  = threadIdx.x;
    int base = tid * (BINS / 256);
    unsigned s = 0;
    for (int i = 0; i < BINS / 256; ++i) s += ghist[base + i];
    csum[tid] = s;
    __syncthreads();
    if (tid == 0) {                       // suffix sums of chunk totals
        unsigned run = 0;
        for (int c = 255; c >= 0; --c) { run += csum[c]; csum[c] = run; }
    }
    __syncthreads();

    unsigned above = (tid == 255) ? 0u : csum[tid + 1];  // cnt_ge[base + chunk]
    unsigned prev = above;
    for (int b = base + BINS / 256 - 1; b >= base; --b) {
        unsigned cur = prev + ghist[b];
        if (cur >= TOPK && prev < TOPK) {
            // b is the unique b*
            unsigned bstar = (unsigned)b;
            unsigned bt = bstar >= SLACK ? bstar - SLACK : 0;
            unsigned cnt = cur;
            for (unsigned bb = bstar; bb-- > bt;) cnt += ghist[bb];
            while (cnt > CAP && bt < bstar) { cnt -= ghist[bt]; bt++; }
            ctrl[1] = bt;
            break;
        }
        prev = cur;
    }
}

// ---------------------------------------------------------------------------
// K4: pass B — recompute qualifying tiles in f64, compact candidates.
// 1024 threads x (4x4 micro-tile) per 128x128 tile.
// ---------------------------------------------------------------------------
__global__ __launch_bounds__(1024) void scores_pass_b(
    const double* __restrict__ Xs64, const double* __restrict__ Xo64,
    const float* __restrict__ tmax, unsigned* __restrict__ ctrl,
    double* __restrict__ cval, unsigned* __restrict__ cidx)
{
    unsigned bt = ctrl[1];
    int tile = blockIdx.y * gridDim.x + blockIdx.x;
    if (binOf(tmax[tile]) < bt) return;

    int tid = threadIdx.x;
    int tr = tid >> 5, tc = tid & 31;
    int r0 = blockIdx.y * 128 + tr * 4;
    int c0 = blockIdx.x * 128 + tc * 4;

    double acc[4][4];
#pragma unroll
    for (int i = 0; i < 4; ++i)
#pragma unroll
        for (int j = 0; j < 4; ++j) acc[i][j] = 0.0;

    const double* As = Xs64 + (size_t)r0 * HID;
    const double* Bs = Xo64 + (size_t)c0 * HID;
    for (int k = 0; k < HID; ++k) {
        double a[4], b[4];
#pragma unroll
        for (int i = 0; i < 4; ++i) a[i] = As[(size_t)i * HID + k];
#pragma unroll
        for (int j = 0; j < 4; ++j) b[j] = Bs[(size_t)j * HID + k];
#pragma unroll
        for (int i = 0; i < 4; ++i)
#pragma unroll
            for (int j = 0; j < 4; ++j)
                acc[i][j] = fma(a[i], b[j], acc[i][j]);
    }

#pragma unroll
    for (int i = 0; i < 4; ++i)
#pragma unroll
        for (int j = 0; j < 4; ++j) {
            int r = r0 + i, c = c0 + j;
            double v = acc[i][j];
            if (r == c) v = -1.0;
            if (binOf((float)v) >= bt) {
                unsigned p = atomicAdd(&ctrl[0], 1u);
                if (p < CAP) {
                    cval[p] = v;
                    cidx[p] = (unsigned)r * (unsigned)NB + (unsigned)c;
                }
            }
        }
}

// ---------------------------------------------------------------------------
// K5: exact top-TOPK via rank-by-counting over M candidates.
// Composite key: value desc, flat index asc (jax top_k tie-break).
// ---------------------------------------------------------------------------
__global__ __launch_bounds__(256) void rank_kernel(
    const unsigned* __restrict__ ctrl,
    const double* __restrict__ cval, const unsigned* __restrict__ cidx,
    double* __restrict__ sval, unsigned* __restrict__ sidx)
{
    unsigned M = ctrl[0];
    if (M > CAP) M = CAP;
    unsigned t = blockIdx.x * 256u + threadIdx.x;
    if (blockIdx.x * 256u >= M) return;

    bool act = t < M;
    double v  = act ? cval[t] : 0.0;
    unsigned id = act ? cidx[t] : 0u;
    unsigned cnt = 0;

    __shared__ double  lv[256];
    __shared__ unsigned li[256];
    for (unsigned base = 0; base < M; base += 256u) {
        unsigned j = base + threadIdx.x;
        if (j < M) { lv[threadIdx.x] = cval[j]; li[threadIdx.x] = cidx[j]; }
        __syncthreads();
        unsigned lim = M - base; if (lim > 256u) lim = 256u;
        if (act) {
            for (unsigned e = 0; e < lim; ++e) {
                double ev = lv[e];
                cnt += (ev > v) || (ev == v && li[e] < id);
            }
        }
        __syncthreads();
    }
    if (act && cnt < TOPK) { sval[cnt] = v; sidx[cnt] = id; }
}

// ---------------------------------------------------------------------------
// K6: union boxes + 0.7*area for the sorted TOPK pairs.
// ---------------------------------------------------------------------------
__global__ __launch_bounds__(256) void nms_prep(
    const unsigned* __restrict__ sidx, const float* __restrict__ rois,
    double* __restrict__ ub)
{
    int t = blockIdx.x * 256 + threadIdx.x;
    if (t >= TOPK) return;
    unsigned id = sidx[t];
    unsigned s = id >> 13, o = id & (NB - 1);
    const float* bs = rois + (size_t)s * 5;
    const float* bo = rois + (size_t)o * 5;
    double x1 = fmin((double)bs[1], (double)bo[1]);
    double y1 = fmin((double)bs[2], (double)bo[2]);
    double x2 = fmax((double)bs[3], (double)bo[3]);
    double y2 = fmax((double)bs[4], (double)bo[4]);
    double area = (x2 - x1) * (y2 - y1);
    double* u = ub + (size_t)t * 5;
    u[0] = x1; u[1] = y1; u[2] = x2; u[3] = y2; u[4] = 0.7 * area;
}

// ---------------------------------------------------------------------------
// K7: suppressed[j] = OR_{i<j} (iou > 0.7). Division-free equivalent:
// inter/(ai+aj-inter+1e-8) > 0.7  <=>  1.7*inter > 0.7*ai + 0.7*aj + 7e-9.
// Grid (jb, ib) tiles of 256x256 pairs.
// ---------------------------------------------------------------------------
__global__ __launch_bounds__(256) void nms_kernel(
    const double* __restrict__ ub, unsigned* __restrict__ sup)
{
    int jb = blockIdx.x, ib = blockIdx.y;
    if (ib > jb) return;
    __shared__ double L[256][5];
    int tid = threadIdx.x;
    int ibase = ib * 256;
    int icount = TOPK - ibase; if (icount > 256) icount = 256;
    if (tid < icount) {
        const double* u = ub + (size_t)(ibase + tid) * 5;
#pragma unroll
        for (int q = 0; q < 5; ++q) L[tid][q] = u[q];
    }
    __syncthreads();

    int j = jb * 256 + tid;
    if (j >= TOPK) return;
    const double* u = ub + (size_t)j * 5;
    double x1 = u[0], y1 = u[1], x2 = u[2], y2 = u[3], pa = u[4];
    int lim = j - ibase; if (lim > icount) lim = icount;  // i < j
    bool flag = false;
    for (int e = 0; e < lim; ++e) {
        double ix1 = fmax(L[e][0], x1);
        double iy1 = fmax(L[e][1], y1);
        double ix2 = fmin(L[e][2], x2);
        double iy2 = fmin(L[e][3], y2);
        double iw = ix2 - ix1; iw = iw > 0.0 ? iw : 0.0;
        double ih = iy2 - iy1; ih = ih > 0.0 ? ih : 0.0;
        double inter = iw * ih;
        if (1.7 * inter > pa + L[e][4] + 7e-9) { flag = true; break; }
    }
    if (flag) atomicOr(&sup[j], 1u);
}

// ---------------------------------------------------------------------------
// K8: top-300 of where(sup,-1,score) over the descending-sorted list is a
// stable partition (unsuppressed first, then suppressed with score -1).
// Single block, chunked LDS scan. Writes all 900 output floats.
// ---------------------------------------------------------------------------
__global__ __launch_bounds__(1024) void finalize_kernel(
    const unsigned* __restrict__ sup, const double* __restrict__ sval,
    const unsigned* __restrict__ sidx, float* __restrict__ out)
{
    __shared__ unsigned pref[1024];
    __shared__ unsigned bases[2];   // running {unsup, sup} counts
    __shared__ unsigned totalu;
    int tid = threadIdx.x;

    unsigned s = 0;
    for (int i = tid; i < TOPK; i += 1024) s += (sup[i] == 0u);
    pref[tid] = s;
    __syncthreads();
    for (int st = 512; st > 0; st >>= 1) {
        if (tid < st) pref[tid] += pref[tid + st];
        __syncthreads();
    }
    if (tid == 0) { totalu = pref[0]; bases[0] = 0; bases[1] = 0; }
    __syncthreads();

    for (int c = 0; c < (TOPK + 1023) / 1024; ++c) {
        int idx = c * 1024 + tid;
        int valid = TOPK - c * 1024; if (valid > 1024) valid = 1024;
        unsigned f = (idx < TOPK && sup[idx] == 0u) ? 1u : 0u;
        pref[tid] = f;
        __syncthreads();
        for (int st = 1; st < 1024; st <<= 1) {
            unsigned add = (tid >= st) ? pref[tid - st] : 0u;
            __syncthreads();
            pref[tid] += add;
            __syncthreads();
        }
        if (idx < TOPK) {
            unsigned incl = pref[tid];
            unsigned e = incl - f;                     // unsup before me in chunk
            unsigned pos = f ? (bases[0] + e)
                             : (totalu + bases[1] + (unsigned)tid - e);
            if (pos < POSTK) {
                unsigned id = sidx[idx];
                unsigned sb = id >> 13, ob = id & (NB - 1);
                out[2 * pos]     = (float)sb;
                out[2 * pos + 1] = (float)ob;
                double sg = f ? 1.0 / (1.0 + exp(-sval[idx])) : -1.0;
                out[2 * POSTK + pos] = (float)sg;
            }
        }
        __syncthreads();
        if (tid == 0) {
            unsigned inclLast = pref[valid - 1];
            bases[0] += inclLast;
            bases[1] += (unsigned)valid - inclLast;
        }
        __syncthreads();
    }
}

// ---------------------------------------------------------------------------
extern "C" void kernel_launch(void* const* d_in, const int* in_sizes, int n_in,
                              void* d_out, int out_size, void* d_ws, size_t ws_size,
                              hipStream_t stream)
{
    const float* rois = (const float*)d_in[0];
    const float* feat = (const float*)d_in[1];
    const float* W1s  = (const float*)d_in[2];
    const float* b1s  = (const float*)d_in[3];
    const float* W2s  = (const float*)d_in[4];
    const float* b2s  = (const float*)d_in[5];
    const float* W1o  = (const float*)d_in[6];
    const float* b1o  = (const float*)d_in[7];
    const float* W2o  = (const float*)d_in[8];
    const float* b2o  = (const float*)d_in[9];

    char* ws = (char*)d_ws;
    size_t off = 0;
    auto alloc = [&](size_t bytes) -> void* {
        off = (off + 255) & ~(size_t)255;
        void* p = ws + off;
        off += bytes;
        return p;
    };

    // zeroed region first
    unsigned* ghist = (unsigned*)alloc((size_t)BINS * 4);     // histogram
    unsigned* ctrl  = (unsigned*)alloc(256);                  // [0]=cand count, [1]=bin threshold
    unsigned* sup   = (unsigned*)alloc((size_t)6144 * 4);     // suppression flags
    size_t zero_bytes = off;

    double* Xs64 = (double*)alloc((size_t)NB * HID * 8);
    double* Xo64 = (double*)alloc((size_t)NB * HID * 8);
    float*  XsT  = (float*)alloc((size_t)NB * HID * 4);
    float*  XoT  = (float*)alloc((size_t)NB * HID * 4);
    float*  tmax = (float*)alloc((size_t)64 * 64 * 4);
    double* cval = (double*)alloc((size_t)CAP * 8);
    unsigned* cidx = (unsigned*)alloc((size_t)CAP * 4);
    double* svalv = (double*)alloc((size_t)TOPK * 8);
    unsigned* sidxv = (unsigned*)alloc((size_t)TOPK * 4);
    double* ub   = (double*)alloc((size_t)TOPK * 5 * 8);

    hipMemsetAsync(d_ws, 0, zero_bytes, stream);

    mlp_kernel<<<NB / 4, 256, 0, stream>>>(feat, W1s, b1s, W2s, b2s,
                                           W1o, b1o, W2o, b2o,
                                           Xs64, Xo64, XsT, XoT);
    scores_pass_a<<<dim3(64, 64), 256, 0, stream>>>(XsT, XoT, ghist, tmax);
    find_threshold<<<1, 256, 0, stream>>>(ghist, ctrl);
    scores_pass_b<<<dim3(64, 64), 1024, 0, stream>>>(Xs64, Xo64, tmax, ctrl, cval, cidx);
    rank_kernel<<<CAP / 256, 256, 0, stream>>>(ctrl, cval, cidx, svalv, sidxv);
    nms_prep<<<(TOPK + 255) / 256, 256, 0, stream>>>(sidxv, rois, ub);
    nms_kernel<<<dim3((TOPK + 255) / 256, (TOPK + 255) / 256), 256, 0, stream>>>(ub, sup);
    finalize_kernel<<<1, 1024, 0, stream>>>(sup, svalv, sidxv, (float*)d_out);
}

// Round 2
// 1579.392 us; speedup vs baseline: 1.7457x; 1.7457x over previous
//
#include <hip/hip_runtime.h>
#include <math.h>

// Problem constants
#define NB    8192          // N
#define FEAT  255
#define HID   64
#define TOPK  6000
#define POSTK 300
#define BINS  8192          // 13-bit sortable-float key bins (sign+8exp+4mant)
#define BSHIFT 19           // 32-13
#define CAP   131072        // candidate buffer capacity
#define SLACK 2             // extra bins below threshold bin (absorbs f32 vs f64 noise)
#define JSLICES 64          // j-dimension parallelism for rank counting

__device__ __forceinline__ unsigned binOf(float x) {
    unsigned u = __float_as_uint(x);
    u = (u & 0x80000000u) ? ~u : (u | 0x80000000u);   // sortable key (ascending)
    return u >> BSHIFT;
}

// ---------------------------------------------------------------------------
// K1: the two 255->64->64 MLPs in f64. One block = 4 rows, 64 threads/row.
// Writes row-major f64 (for pass B) and transposed f32 [k][n] (for pass A).
// ---------------------------------------------------------------------------
__global__ __launch_bounds__(256) void mlp_kernel(
    const float* __restrict__ feat,
    const float* __restrict__ W1s, const float* __restrict__ b1s,
    const float* __restrict__ W2s, const float* __restrict__ b2s,
    const float* __restrict__ W1o, const float* __restrict__ b1o,
    const float* __restrict__ W2o, const float* __restrict__ b2o,
    double* __restrict__ Xs64, double* __restrict__ Xo64,
    float* __restrict__ XsT, float* __restrict__ XoT)
{
    int tid  = threadIdx.x;
    int trow = tid >> 6;          // 0..3
    int t    = tid & 63;          // hidden unit
    int r    = blockIdx.x * 4 + trow;
    __shared__ double hs[4][64];
    __shared__ double ho[4][64];

    const float* frow = feat + (size_t)r * FEAT;
    double as = (double)b1s[t];
    double ao = (double)b1o[t];
    for (int k = 0; k < FEAT; ++k) {
        double fv = (double)frow[k];
        as += fv * (double)W1s[k * HID + t];
        ao += fv * (double)W1o[k * HID + t];
    }
    hs[trow][t] = as > 0.0 ? as : 0.0;
    ho[trow][t] = ao > 0.0 ? ao : 0.0;
    __syncthreads();

    double xs = (double)b2s[t];
    double xo = (double)b2o[t];
    for (int k = 0; k < HID; ++k) {
        xs += hs[trow][k] * (double)W2s[k * HID + t];
        xo += ho[trow][k] * (double)W2o[k * HID + t];
    }
    size_t o = (size_t)r * HID + t;
    Xs64[o] = xs;
    Xo64[o] = xo;
    XsT[(size_t)t * NB + r] = (float)xs;   // [k][n] layout for coalesced pass A
    XoT[(size_t)t * NB + r] = (float)xo;
}

// ---------------------------------------------------------------------------
// K2: pass A — f32 logits for all 8192^2 pairs. 128x128 tile / block,
// 256 threads x (8x8 micro-tile). Histogram keys in LDS, merge sparse bins.
// Also records per-tile max for pass-B tile skipping.
// ---------------------------------------------------------------------------
__global__ __launch_bounds__(256) void scores_pass_a(
    const float* __restrict__ XsT, const float* __restrict__ XoT,
    unsigned* __restrict__ ghist, float* __restrict__ tmax)
{
    __shared__ unsigned hist[BINS];   // 32 KB
    __shared__ float smax[256];
    int tid = threadIdx.x;
    for (int i = tid; i < BINS; i += 256) hist[i] = 0u;
    __syncthreads();

    int tr = tid >> 4, tc = tid & 15;
    int r0 = blockIdx.y * 128 + tr * 8;
    int c0 = blockIdx.x * 128 + tc * 8;

    float acc[8][8];
#pragma unroll
    for (int i = 0; i < 8; ++i)
#pragma unroll
        for (int j = 0; j < 8; ++j) acc[i][j] = 0.0f;

    for (int k = 0; k < HID; ++k) {
        const float4* ap = (const float4*)(XsT + (size_t)k * NB + r0);
        const float4* bp = (const float4*)(XoT + (size_t)k * NB + c0);
        float4 a0 = ap[0], a1 = ap[1];
        float4 b0 = bp[0], b1 = bp[1];
        float a[8] = {a0.x, a0.y, a0.z, a0.w, a1.x, a1.y, a1.z, a1.w};
        float b[8] = {b0.x, b0.y, b0.z, b0.w, b1.x, b1.y, b1.z, b1.w};
#pragma unroll
        for (int i = 0; i < 8; ++i)
#pragma unroll
            for (int j = 0; j < 8; ++j)
                acc[i][j] = fmaf(a[i], b[j], acc[i][j]);
    }

    float vmax = -3.0e38f;
#pragma unroll
    for (int i = 0; i < 8; ++i)
#pragma unroll
        for (int j = 0; j < 8; ++j) {
            float v = acc[i][j];
            if (r0 + i == c0 + j) v = -1.0f;      // diagonal, like reference
            vmax = fmaxf(vmax, v);
            atomicAdd(&hist[binOf(v)], 1u);
        }

    smax[tid] = vmax;
    __syncthreads();
    for (int st = 128; st > 0; st >>= 1) {
        if (tid < st) smax[tid] = fmaxf(smax[tid], smax[tid + st]);
        __syncthreads();
    }
    if (tid == 0) tmax[blockIdx.y * gridDim.x + blockIdx.x] = smax[0];

    for (int i = tid; i < BINS; i += 256) {
        unsigned h = hist[i];
        if (h) atomicAdd(&ghist[i], h);
    }
}

// ---------------------------------------------------------------------------
// K3: find threshold bin b* (largest b with cnt_ge[b] >= TOPK); write
// ctrl[1] = b* - SLACK (raised if candidate count would exceed CAP).
// ---------------------------------------------------------------------------
__global__ __launch_bounds__(256) void find_threshold(
    const unsigned* __restrict__ ghist, unsigned* __restrict__ ctrl)
{
    __shared__ unsigned csum[256];
    int tid  = threadIdx.x;
    int base = tid * (BINS / 256);
    unsigned s = 0;
    for (int i = 0; i < BINS / 256; ++i) s += ghist[base + i];
    csum[tid] = s;
    __syncthreads();
    if (tid == 0) {                       // suffix sums of chunk totals
        unsigned run = 0;
        for (int c = 255; c >= 0; --c) { run += csum[c]; csum[c] = run; }
    }
    __syncthreads();

    unsigned above = (tid == 255) ? 0u : csum[tid + 1];  // cnt_ge[base + chunk]
    unsigned prev = above;
    for (int b = base + BINS / 256 - 1; b >= base; --b) {
        unsigned cur = prev + ghist[b];
        if (cur >= TOPK && prev < TOPK) {
            // b is the unique b*
            unsigned bstar = (unsigned)b;
            unsigned bt = bstar >= SLACK ? bstar - SLACK : 0;
            unsigned cnt = cur;
            for (unsigned bb = bstar; bb-- > bt;) cnt += ghist[bb];
            while (cnt > CAP && bt < bstar) { cnt -= ghist[bt]; bt++; }
            ctrl[1] = bt;
            break;
        }
        prev = cur;
    }
}

// ---------------------------------------------------------------------------
// K4: pass B — recompute qualifying tiles in f64, compact candidates.
// 1024 threads x (4x4 micro-tile) per 128x128 tile.
// ---------------------------------------------------------------------------
__global__ __launch_bounds__(1024) void scores_pass_b(
    const double* __restrict__ Xs64, const double* __restrict__ Xo64,
    const float* __restrict__ tmax, unsigned* __restrict__ ctrl,
    double* __restrict__ cval, unsigned* __restrict__ cidx)
{
    unsigned bt = ctrl[1];
    int tile = blockIdx.y * gridDim.x + blockIdx.x;
    if (binOf(tmax[tile]) < bt) return;

    int tid = threadIdx.x;
    int tr = tid >> 5, tc = tid & 31;
    int r0 = blockIdx.y * 128 + tr * 4;
    int c0 = blockIdx.x * 128 + tc * 4;

    double acc[4][4];
#pragma unroll
    for (int i = 0; i < 4; ++i)
#pragma unroll
        for (int j = 0; j < 4; ++j) acc[i][j] = 0.0;

    const double* As = Xs64 + (size_t)r0 * HID;
    const double* Bs = Xo64 + (size_t)c0 * HID;
    for (int k = 0; k < HID; ++k) {
        double a[4], b[4];
#pragma unroll
        for (int i = 0; i < 4; ++i) a[i] = As[(size_t)i * HID + k];
#pragma unroll
        for (int j = 0; j < 4; ++j) b[j] = Bs[(size_t)j * HID + k];
#pragma unroll
        for (int i = 0; i < 4; ++i)
#pragma unroll
            for (int j = 0; j < 4; ++j)
                acc[i][j] = fma(a[i], b[j], acc[i][j]);
    }

#pragma unroll
    for (int i = 0; i < 4; ++i)
#pragma unroll
        for (int j = 0; j < 4; ++j) {
            int r = r0 + i, c = c0 + j;
            double v = acc[i][j];
            if (r == c) v = -1.0;
            if (binOf((float)v) >= bt) {
                unsigned p = atomicAdd(&ctrl[0], 1u);
                if (p < CAP) {
                    cval[p] = v;
                    cidx[p] = (unsigned)r * (unsigned)NB + (unsigned)c;
                }
            }
        }
}

// ---------------------------------------------------------------------------
// K5a: rank-by-counting, 2-D parallel. Grid (i_tile, j_slice). Each block
// counts its 256 candidates against one j-slice (LDS-staged 256 at a time)
// and atomically accumulates into rank[]. Composite key: value desc, flat
// index asc (jax top_k tie-break).
// ---------------------------------------------------------------------------
__global__ __launch_bounds__(256) void rank_count(
    const unsigned* __restrict__ ctrl,
    const double* __restrict__ cval, const unsigned* __restrict__ cidx,
    unsigned* __restrict__ rank)
{
    unsigned M = ctrl[0];
    if (M > CAP) M = CAP;
    unsigned itile = blockIdx.x;
    if (itile * 256u >= M) return;

    unsigned t = itile * 256u + threadIdx.x;
    bool act = t < M;
    double v  = act ? cval[t] : 0.0;
    unsigned id = act ? cidx[t] : 0u;
    unsigned cnt = 0;

    // j-slice range
    unsigned slice = blockIdx.y;
    unsigned jbeg = (unsigned)(((unsigned long long)slice * M) / JSLICES);
    unsigned jend = (unsigned)(((unsigned long long)(slice + 1) * M) / JSLICES);

    __shared__ double  lv[256];
    __shared__ unsigned li[256];
    for (unsigned base = jbeg; base < jend; base += 256u) {
        unsigned j = base + threadIdx.x;
        if (j < jend) { lv[threadIdx.x] = cval[j]; li[threadIdx.x] = cidx[j]; }
        __syncthreads();
        unsigned lim = jend - base; if (lim > 256u) lim = 256u;
        if (act) {
            for (unsigned e = 0; e < lim; ++e) {
                double ev = lv[e];
                cnt += (ev > v) || (ev == v && li[e] < id);
            }
        }
        __syncthreads();
    }
    if (act && cnt) atomicAdd(&rank[t], cnt);
}

// ---------------------------------------------------------------------------
// K5b: scatter candidates with rank < TOPK into sorted arrays.
// ---------------------------------------------------------------------------
__global__ __launch_bounds__(256) void rank_scatter(
    const unsigned* __restrict__ ctrl,
    const double* __restrict__ cval, const unsigned* __restrict__ cidx,
    const unsigned* __restrict__ rank,
    double* __restrict__ sval, unsigned* __restrict__ sidx)
{
    unsigned M = ctrl[0];
    if (M > CAP) M = CAP;
    unsigned t = blockIdx.x * 256u + threadIdx.x;
    if (t >= M) return;
    unsigned r = rank[t];
    if (r < TOPK) { sval[r] = cval[t]; sidx[r] = cidx[t]; }
}

// ---------------------------------------------------------------------------
// K6: union boxes + 0.7*area for the sorted TOPK pairs.
// ---------------------------------------------------------------------------
__global__ __launch_bounds__(256) void nms_prep(
    const unsigned* __restrict__ sidx, const float* __restrict__ rois,
    double* __restrict__ ub)
{
    int t = blockIdx.x * 256 + threadIdx.x;
    if (t >= TOPK) return;
    unsigned id = sidx[t];
    unsigned s = id >> 13, o = id & (NB - 1);
    const float* bs = rois + (size_t)s * 5;
    const float* bo = rois + (size_t)o * 5;
    double x1 = fmin((double)bs[1], (double)bo[1]);
    double y1 = fmin((double)bs[2], (double)bo[2]);
    double x2 = fmax((double)bs[3], (double)bo[3]);
    double y2 = fmax((double)bs[4], (double)bo[4]);
    double area = (x2 - x1) * (y2 - y1);
    double* u = ub + (size_t)t * 5;
    u[0] = x1; u[1] = y1; u[2] = x2; u[3] = y2; u[4] = 0.7 * area;
}

// ---------------------------------------------------------------------------
// K7: suppressed[j] = OR_{i<j} (iou > 0.7). Division-free equivalent:
// inter/(ai+aj-inter+1e-8) > 0.7  <=>  1.7*inter > 0.7*ai + 0.7*aj + 7e-9.
// Grid (jb, ib) tiles of 256x256 pairs.
// ---------------------------------------------------------------------------
__global__ __launch_bounds__(256) void nms_kernel(
    const double* __restrict__ ub, unsigned* __restrict__ sup)
{
    int jb = blockIdx.x, ib = blockIdx.y;
    if (ib > jb) return;
    __shared__ double L[256][5];
    int tid = threadIdx.x;
    int ibase = ib * 256;
    int icount = TOPK - ibase; if (icount > 256) icount = 256;
    if (tid < icount) {
        const double* u = ub + (size_t)(ibase + tid) * 5;
#pragma unroll
        for (int q = 0; q < 5; ++q) L[tid][q] = u[q];
    }
    __syncthreads();

    int j = jb * 256 + tid;
    if (j >= TOPK) return;
    const double* u = ub + (size_t)j * 5;
    double x1 = u[0], y1 = u[1], x2 = u[2], y2 = u[3], pa = u[4];
    int lim = j - ibase; if (lim > icount) lim = icount;  // i < j
    bool flag = false;
    for (int e = 0; e < lim; ++e) {
        double ix1 = fmax(L[e][0], x1);
        double iy1 = fmax(L[e][1], y1);
        double ix2 = fmin(L[e][2], x2);
        double iy2 = fmin(L[e][3], y2);
        double iw = ix2 - ix1; iw = iw > 0.0 ? iw : 0.0;
        double ih = iy2 - iy1; ih = ih > 0.0 ? ih : 0.0;
        double inter = iw * ih;
        if (1.7 * inter > pa + L[e][4] + 7e-9) { flag = true; break; }
    }
    if (flag) atomicOr(&sup[j], 1u);
}

// ---------------------------------------------------------------------------
// K8: top-300 of where(sup,-1,score) over the descending-sorted list is a
// stable partition (unsuppressed first, then suppressed with score -1).
// Single block, chunked LDS scan. Writes all 900 output floats.
// ---------------------------------------------------------------------------
__global__ __launch_bounds__(1024) void finalize_kernel(
    const unsigned* __restrict__ sup, const double* __restrict__ sval,
    const unsigned* __restrict__ sidx, float* __restrict__ out)
{
    __shared__ unsigned pref[1024];
    __shared__ unsigned bases[2];   // running {unsup, sup} counts
    __shared__ unsigned totalu;
    int tid = threadIdx.x;

    unsigned s = 0;
    for (int i = tid; i < TOPK; i += 1024) s += (sup[i] == 0u);
    pref[tid] = s;
    __syncthreads();
    for (int st = 512; st > 0; st >>= 1) {
        if (tid < st) pref[tid] += pref[tid + st];
        __syncthreads();
    }
    if (tid == 0) { totalu = pref[0]; bases[0] = 0; bases[1] = 0; }
    __syncthreads();

    for (int c = 0; c < (TOPK + 1023) / 1024; ++c) {
        int idx = c * 1024 + tid;
        int valid = TOPK - c * 1024; if (valid > 1024) valid = 1024;
        unsigned f = (idx < TOPK && sup[idx] == 0u) ? 1u : 0u;
        pref[tid] = f;
        __syncthreads();
        for (int st = 1; st < 1024; st <<= 1) {
            unsigned add = (tid >= st) ? pref[tid - st] : 0u;
            __syncthreads();
            pref[tid] += add;
            __syncthreads();
        }
        if (idx < TOPK) {
            unsigned incl = pref[tid];
            unsigned e = incl - f;                     // unsup before me in chunk
            unsigned pos = f ? (bases[0] + e)
                             : (totalu + bases[1] + (unsigned)tid - e);
            if (pos < POSTK) {
                unsigned id = sidx[idx];
                unsigned sb = id >> 13, ob = id & (NB - 1);
                out[2 * pos]     = (float)sb;
                out[2 * pos + 1] = (float)ob;
                double sg = f ? 1.0 / (1.0 + exp(-sval[idx])) : -1.0;
                out[2 * POSTK + pos] = (float)sg;
            }
        }
        __syncthreads();
        if (tid == 0) {
            unsigned inclLast = pref[valid - 1];
            bases[0] += inclLast;
            bases[1] += (unsigned)valid - inclLast;
        }
        __syncthreads();
    }
}

// ---------------------------------------------------------------------------
extern "C" void kernel_launch(void* const* d_in, const int* in_sizes, int n_in,
                              void* d_out, int out_size, void* d_ws, size_t ws_size,
                              hipStream_t stream)
{
    const float* rois = (const float*)d_in[0];
    const float* feat = (const float*)d_in[1];
    const float* W1s  = (const float*)d_in[2];
    const float* b1s  = (const float*)d_in[3];
    const float* W2s  = (const float*)d_in[4];
    const float* b2s  = (const float*)d_in[5];
    const float* W1o  = (const float*)d_in[6];
    const float* b1o  = (const float*)d_in[7];
    const float* W2o  = (const float*)d_in[8];
    const float* b2o  = (const float*)d_in[9];

    char* ws = (char*)d_ws;
    size_t off = 0;
    auto alloc = [&](size_t bytes) -> void* {
        off = (off + 255) & ~(size_t)255;
        void* p = ws + off;
        off += bytes;
        return p;
    };

    // zeroed region first
    unsigned* ghist = (unsigned*)alloc((size_t)BINS * 4);     // histogram
    unsigned* ctrl  = (unsigned*)alloc(256);                  // [0]=cand count, [1]=bin threshold
    unsigned* sup   = (unsigned*)alloc((size_t)6144 * 4);     // suppression flags
    unsigned* rank  = (unsigned*)alloc((size_t)CAP * 4);      // candidate ranks
    size_t zero_bytes = off;

    double* Xs64 = (double*)alloc((size_t)NB * HID * 8);
    double* Xo64 = (double*)alloc((size_t)NB * HID * 8);
    float*  XsT  = (float*)alloc((size_t)NB * HID * 4);
    float*  XoT  = (float*)alloc((size_t)NB * HID * 4);
    float*  tmax = (float*)alloc((size_t)64 * 64 * 4);
    double* cval = (double*)alloc((size_t)CAP * 8);
    unsigned* cidx = (unsigned*)alloc((size_t)CAP * 4);
    double* svalv = (double*)alloc((size_t)TOPK * 8);
    unsigned* sidxv = (unsigned*)alloc((size_t)TOPK * 4);
    double* ub   = (double*)alloc((size_t)TOPK * 5 * 8);

    hipMemsetAsync(d_ws, 0, zero_bytes, stream);

    mlp_kernel<<<NB / 4, 256, 0, stream>>>(feat, W1s, b1s, W2s, b2s,
                                           W1o, b1o, W2o, b2o,
                                           Xs64, Xo64, XsT, XoT);
    scores_pass_a<<<dim3(64, 64), 256, 0, stream>>>(XsT, XoT, ghist, tmax);
    find_threshold<<<1, 256, 0, stream>>>(ghist, ctrl);
    scores_pass_b<<<dim3(64, 64), 1024, 0, stream>>>(Xs64, Xo64, tmax, ctrl, cval, cidx);
    rank_count<<<dim3(CAP / 256, JSLICES), 256, 0, stream>>>(ctrl, cval, cidx, rank);
    rank_scatter<<<CAP / 256, 256, 0, stream>>>(ctrl, cval, cidx, rank, svalv, sidxv);
    nms_prep<<<(TOPK + 255) / 256, 256, 0, stream>>>(sidxv, rois, ub);
    nms_kernel<<<dim3((TOPK + 255) / 256, (TOPK + 255) / 256), 256, 0, stream>>>(ub, sup);
    finalize_kernel<<<1, 1024, 0, stream>>>(sup, svalv, sidxv, (float*)d_out);
}

// Round 3
// 677.873 us; speedup vs baseline: 4.0673x; 2.3299x over previous
//
#include <hip/hip_runtime.h>
#include <math.h>

// Problem constants
#define NB    8192          // N
#define FEAT  255
#define HID   64
#define TOPK  6000
#define POSTK 300
#define BINS  8192          // 13-bit sortable-float key bins (sign+8exp+4mant)
#define BSHIFT 19           // 32-13
#define CAP   65536         // candidate buffer capacity (bounds rank_count work)
#define SLACK 2             // extra bins below threshold bin (absorbs f32 vs f64 noise)
#define JSLICES 64          // j-dimension parallelism for rank counting

__device__ __forceinline__ unsigned binOf(float x) {
    unsigned u = __float_as_uint(x);
    u = (u & 0x80000000u) ? ~u : (u | 0x80000000u);   // sortable key (ascending)
    return u >> BSHIFT;
}

// ---------------------------------------------------------------------------
// K1: the two 255->64->64 MLPs in f64. One block = 4 rows, 64 threads/row.
// Writes row-major f64 (for candidate refine) and transposed f32 [k][n].
// ---------------------------------------------------------------------------
__global__ __launch_bounds__(256) void mlp_kernel(
    const float* __restrict__ feat,
    const float* __restrict__ W1s, const float* __restrict__ b1s,
    const float* __restrict__ W2s, const float* __restrict__ b2s,
    const float* __restrict__ W1o, const float* __restrict__ b1o,
    const float* __restrict__ W2o, const float* __restrict__ b2o,
    double* __restrict__ Xs64, double* __restrict__ Xo64,
    float* __restrict__ XsT, float* __restrict__ XoT)
{
    int tid  = threadIdx.x;
    int trow = tid >> 6;          // 0..3
    int t    = tid & 63;          // hidden unit
    int r    = blockIdx.x * 4 + trow;
    __shared__ double hs[4][64];
    __shared__ double ho[4][64];

    const float* frow = feat + (size_t)r * FEAT;
    double as = (double)b1s[t];
    double ao = (double)b1o[t];
    for (int k = 0; k < FEAT; ++k) {
        double fv = (double)frow[k];
        as += fv * (double)W1s[k * HID + t];
        ao += fv * (double)W1o[k * HID + t];
    }
    hs[trow][t] = as > 0.0 ? as : 0.0;
    ho[trow][t] = ao > 0.0 ? ao : 0.0;
    __syncthreads();

    double xs = (double)b2s[t];
    double xo = (double)b2o[t];
    for (int k = 0; k < HID; ++k) {
        xs += hs[trow][k] * (double)W2s[k * HID + t];
        xo += ho[trow][k] * (double)W2o[k * HID + t];
    }
    size_t o = (size_t)r * HID + t;
    Xs64[o] = xs;
    Xo64[o] = xo;
    XsT[(size_t)t * NB + r] = (float)xs;   // [k][n] layout for coalesced pass A
    XoT[(size_t)t * NB + r] = (float)xo;
}

// ---------------------------------------------------------------------------
// K2: pass A — f32 logits for all 8192^2 pairs. 128x128 tile / block,
// 256 threads x (8x8 micro-tile). Histogram of sortable keys in LDS,
// merged into global histogram.
// ---------------------------------------------------------------------------
__global__ __launch_bounds__(256) void scores_pass_a(
    const float* __restrict__ XsT, const float* __restrict__ XoT,
    unsigned* __restrict__ ghist)
{
    __shared__ unsigned hist[BINS];   // 32 KB
    int tid = threadIdx.x;
    for (int i = tid; i < BINS; i += 256) hist[i] = 0u;
    __syncthreads();

    int tr = tid >> 4, tc = tid & 15;
    int r0 = blockIdx.y * 128 + tr * 8;
    int c0 = blockIdx.x * 128 + tc * 8;

    float acc[8][8];
#pragma unroll
    for (int i = 0; i < 8; ++i)
#pragma unroll
        for (int j = 0; j < 8; ++j) acc[i][j] = 0.0f;

    for (int k = 0; k < HID; ++k) {
        const float4* ap = (const float4*)(XsT + (size_t)k * NB + r0);
        const float4* bp = (const float4*)(XoT + (size_t)k * NB + c0);
        float4 a0 = ap[0], a1 = ap[1];
        float4 b0 = bp[0], b1 = bp[1];
        float a[8] = {a0.x, a0.y, a0.z, a0.w, a1.x, a1.y, a1.z, a1.w};
        float b[8] = {b0.x, b0.y, b0.z, b0.w, b1.x, b1.y, b1.z, b1.w};
#pragma unroll
        for (int i = 0; i < 8; ++i)
#pragma unroll
            for (int j = 0; j < 8; ++j)
                acc[i][j] = fmaf(a[i], b[j], acc[i][j]);
    }

#pragma unroll
    for (int i = 0; i < 8; ++i)
#pragma unroll
        for (int j = 0; j < 8; ++j) {
            float v = acc[i][j];
            if (r0 + i == c0 + j) v = -1.0f;      // diagonal, like reference
            atomicAdd(&hist[binOf(v)], 1u);
        }

    __syncthreads();
    for (int i = tid; i < BINS; i += 256) {
        unsigned h = hist[i];
        if (h) atomicAdd(&ghist[i], h);
    }
}

// ---------------------------------------------------------------------------
// K3: find threshold bin b* (largest b with cnt_ge[b] >= TOPK); write
// ctrl[1] = b* - SLACK (raised if candidate count would exceed CAP).
// ---------------------------------------------------------------------------
__global__ __launch_bounds__(256) void find_threshold(
    const unsigned* __restrict__ ghist, unsigned* __restrict__ ctrl)
{
    __shared__ unsigned csum[256];
    int tid  = threadIdx.x;
    int base = tid * (BINS / 256);
    unsigned s = 0;
    for (int i = 0; i < BINS / 256; ++i) s += ghist[base + i];
    csum[tid] = s;
    __syncthreads();
    if (tid == 0) {                       // suffix sums of chunk totals
        unsigned run = 0;
        for (int c = 255; c >= 0; --c) { run += csum[c]; csum[c] = run; }
    }
    __syncthreads();

    unsigned above = (tid == 255) ? 0u : csum[tid + 1];  // cnt_ge[base + chunk]
    unsigned prev = above;
    for (int b = base + BINS / 256 - 1; b >= base; --b) {
        unsigned cur = prev + ghist[b];
        if (cur >= TOPK && prev < TOPK) {
            // b is the unique b*
            unsigned bstar = (unsigned)b;
            unsigned bt = bstar >= SLACK ? bstar - SLACK : 0;
            unsigned cnt = cur;
            for (unsigned bb = bstar; bb-- > bt;) cnt += ghist[bb];
            while (cnt > CAP && bt < bstar) { cnt -= ghist[bt]; bt++; }
            ctrl[1] = bt;
            break;
        }
        prev = cur;
    }
}

// ---------------------------------------------------------------------------
// K4: pass B — recompute f32 GEMM; elements whose f32 bin clears the
// threshold get an exact f64 dot (same sequential-k accumulation order as
// the reference path) and are compacted into the candidate buffer.
// Candidate count == histogram count >= bt, which find_threshold bounded
// to <= CAP, so no overflow is possible.
// ---------------------------------------------------------------------------
__global__ __launch_bounds__(256) void scores_pass_b(
    const float* __restrict__ XsT, const float* __restrict__ XoT,
    const double* __restrict__ Xs64, const double* __restrict__ Xo64,
    unsigned* __restrict__ ctrl,
    double* __restrict__ cval, unsigned* __restrict__ cidx)
{
    unsigned bt = ctrl[1];
    int tid = threadIdx.x;
    int tr = tid >> 4, tc = tid & 15;
    int r0 = blockIdx.y * 128 + tr * 8;
    int c0 = blockIdx.x * 128 + tc * 8;

    float acc[8][8];
#pragma unroll
    for (int i = 0; i < 8; ++i)
#pragma unroll
        for (int j = 0; j < 8; ++j) acc[i][j] = 0.0f;

    for (int k = 0; k < HID; ++k) {
        const float4* ap = (const float4*)(XsT + (size_t)k * NB + r0);
        const float4* bp = (const float4*)(XoT + (size_t)k * NB + c0);
        float4 a0 = ap[0], a1 = ap[1];
        float4 b0 = bp[0], b1 = bp[1];
        float a[8] = {a0.x, a0.y, a0.z, a0.w, a1.x, a1.y, a1.z, a1.w};
        float b[8] = {b0.x, b0.y, b0.z, b0.w, b1.x, b1.y, b1.z, b1.w};
#pragma unroll
        for (int i = 0; i < 8; ++i)
#pragma unroll
            for (int j = 0; j < 8; ++j)
                acc[i][j] = fmaf(a[i], b[j], acc[i][j]);
    }

#pragma unroll
    for (int i = 0; i < 8; ++i)
#pragma unroll
        for (int j = 0; j < 8; ++j) {
            int r = r0 + i, c = c0 + j;
            float v = acc[i][j];
            if (r == c) v = -1.0f;
            if (binOf(v) >= bt) {
                // exact f64 refine (rare path)
                double vd;
                if (r == c) {
                    vd = -1.0;
                } else {
                    const double* As = Xs64 + (size_t)r * HID;
                    const double* Bs = Xo64 + (size_t)c * HID;
                    vd = 0.0;
#pragma unroll 8
                    for (int k = 0; k < HID; ++k)
                        vd = fma(As[k], Bs[k], vd);
                }
                unsigned p = atomicAdd(&ctrl[0], 1u);
                if (p < CAP) {
                    cval[p] = vd;
                    cidx[p] = (unsigned)r * (unsigned)NB + (unsigned)c;
                }
            }
        }
}

// ---------------------------------------------------------------------------
// K5a: rank-by-counting, 2-D parallel. Grid (i_tile, j_slice). Each block
// counts its 256 candidates against one j-slice (LDS-staged 256 at a time)
// and atomically accumulates into rank[]. Composite key: value desc, flat
// index asc (jax top_k tie-break).
// ---------------------------------------------------------------------------
__global__ __launch_bounds__(256) void rank_count(
    const unsigned* __restrict__ ctrl,
    const double* __restrict__ cval, const unsigned* __restrict__ cidx,
    unsigned* __restrict__ rank)
{
    unsigned M = ctrl[0];
    if (M > CAP) M = CAP;
    unsigned itile = blockIdx.x;
    if (itile * 256u >= M) return;

    unsigned t = itile * 256u + threadIdx.x;
    bool act = t < M;
    double v  = act ? cval[t] : 0.0;
    unsigned id = act ? cidx[t] : 0u;
    unsigned cnt = 0;

    // j-slice range
    unsigned slice = blockIdx.y;
    unsigned jbeg = (unsigned)(((unsigned long long)slice * M) / JSLICES);
    unsigned jend = (unsigned)(((unsigned long long)(slice + 1) * M) / JSLICES);

    __shared__ double  lv[256];
    __shared__ unsigned li[256];
    for (unsigned base = jbeg; base < jend; base += 256u) {
        unsigned j = base + threadIdx.x;
        if (j < jend) { lv[threadIdx.x] = cval[j]; li[threadIdx.x] = cidx[j]; }
        __syncthreads();
        unsigned lim = jend - base; if (lim > 256u) lim = 256u;
        if (act) {
            for (unsigned e = 0; e < lim; ++e) {
                double ev = lv[e];
                cnt += (ev > v) || (ev == v && li[e] < id);
            }
        }
        __syncthreads();
    }
    if (act && cnt) atomicAdd(&rank[t], cnt);
}

// ---------------------------------------------------------------------------
// K5b: scatter candidates with rank < TOPK into sorted arrays.
// ---------------------------------------------------------------------------
__global__ __launch_bounds__(256) void rank_scatter(
    const unsigned* __restrict__ ctrl,
    const double* __restrict__ cval, const unsigned* __restrict__ cidx,
    const unsigned* __restrict__ rank,
    double* __restrict__ sval, unsigned* __restrict__ sidx)
{
    unsigned M = ctrl[0];
    if (M > CAP) M = CAP;
    unsigned t = blockIdx.x * 256u + threadIdx.x;
    if (t >= M) return;
    unsigned r = rank[t];
    if (r < TOPK) { sval[r] = cval[t]; sidx[r] = cidx[t]; }
}

// ---------------------------------------------------------------------------
// K6: union boxes + 0.7*area for the sorted TOPK pairs.
// ---------------------------------------------------------------------------
__global__ __launch_bounds__(256) void nms_prep(
    const unsigned* __restrict__ sidx, const float* __restrict__ rois,
    double* __restrict__ ub)
{
    int t = blockIdx.x * 256 + threadIdx.x;
    if (t >= TOPK) return;
    unsigned id = sidx[t];
    unsigned s = id >> 13, o = id & (NB - 1);
    const float* bs = rois + (size_t)s * 5;
    const float* bo = rois + (size_t)o * 5;
    double x1 = fmin((double)bs[1], (double)bo[1]);
    double y1 = fmin((double)bs[2], (double)bo[2]);
    double x2 = fmax((double)bs[3], (double)bo[3]);
    double y2 = fmax((double)bs[4], (double)bo[4]);
    double area = (x2 - x1) * (y2 - y1);
    double* u = ub + (size_t)t * 5;
    u[0] = x1; u[1] = y1; u[2] = x2; u[3] = y2; u[4] = 0.7 * area;
}

// ---------------------------------------------------------------------------
// K7: suppressed[j] = OR_{i<j} (iou > 0.7). Division-free equivalent:
// inter/(ai+aj-inter+1e-8) > 0.7  <=>  1.7*inter > 0.7*ai + 0.7*aj + 7e-9.
// Grid (jb, ib) tiles of 256x256 pairs.
// ---------------------------------------------------------------------------
__global__ __launch_bounds__(256) void nms_kernel(
    const double* __restrict__ ub, unsigned* __restrict__ sup)
{
    int jb = blockIdx.x, ib = blockIdx.y;
    if (ib > jb) return;
    __shared__ double L[256][5];
    int tid = threadIdx.x;
    int ibase = ib * 256;
    int icount = TOPK - ibase; if (icount > 256) icount = 256;
    if (tid < icount) {
        const double* u = ub + (size_t)(ibase + tid) * 5;
#pragma unroll
        for (int q = 0; q < 5; ++q) L[tid][q] = u[q];
    }
    __syncthreads();

    int j = jb * 256 + tid;
    if (j >= TOPK) return;
    const double* u = ub + (size_t)j * 5;
    double x1 = u[0], y1 = u[1], x2 = u[2], y2 = u[3], pa = u[4];
    int lim = j - ibase; if (lim > icount) lim = icount;  // i < j
    bool flag = false;
    for (int e = 0; e < lim; ++e) {
        double ix1 = fmax(L[e][0], x1);
        double iy1 = fmax(L[e][1], y1);
        double ix2 = fmin(L[e][2], x2);
        double iy2 = fmin(L[e][3], y2);
        double iw = ix2 - ix1; iw = iw > 0.0 ? iw : 0.0;
        double ih = iy2 - iy1; ih = ih > 0.0 ? ih : 0.0;
        double inter = iw * ih;
        if (1.7 * inter > pa + L[e][4] + 7e-9) { flag = true; break; }
    }
    if (flag) atomicOr(&sup[j], 1u);
}

// ---------------------------------------------------------------------------
// K8: top-300 of where(sup,-1,score) over the descending-sorted list is a
// stable partition (unsuppressed first, then suppressed with score -1).
// Single block, chunked LDS scan. Writes all 900 output floats.
// ---------------------------------------------------------------------------
__global__ __launch_bounds__(1024) void finalize_kernel(
    const unsigned* __restrict__ sup, const double* __restrict__ sval,
    const unsigned* __restrict__ sidx, float* __restrict__ out)
{
    __shared__ unsigned pref[1024];
    __shared__ unsigned bases[2];   // running {unsup, sup} counts
    __shared__ unsigned totalu;
    int tid = threadIdx.x;

    unsigned s = 0;
    for (int i = tid; i < TOPK; i += 1024) s += (sup[i] == 0u);
    pref[tid] = s;
    __syncthreads();
    for (int st = 512; st > 0; st >>= 1) {
        if (tid < st) pref[tid] += pref[tid + st];
        __syncthreads();
    }
    if (tid == 0) { totalu = pref[0]; bases[0] = 0; bases[1] = 0; }
    __syncthreads();

    for (int c = 0; c < (TOPK + 1023) / 1024; ++c) {
        int idx = c * 1024 + tid;
        int valid = TOPK - c * 1024; if (valid > 1024) valid = 1024;
        unsigned f = (idx < TOPK && sup[idx] == 0u) ? 1u : 0u;
        pref[tid] = f;
        __syncthreads();
        for (int st = 1; st < 1024; st <<= 1) {
            unsigned add = (tid >= st) ? pref[tid - st] : 0u;
            __syncthreads();
            pref[tid] += add;
            __syncthreads();
        }
        if (idx < TOPK) {
            unsigned incl = pref[tid];
            unsigned e = incl - f;                     // unsup before me in chunk
            unsigned pos = f ? (bases[0] + e)
                             : (totalu + bases[1] + (unsigned)tid - e);
            if (pos < POSTK) {
                unsigned id = sidx[idx];
                unsigned sb = id >> 13, ob = id & (NB - 1);
                out[2 * pos]     = (float)sb;
                out[2 * pos + 1] = (float)ob;
                double sg = f ? 1.0 / (1.0 + exp(-sval[idx])) : -1.0;
                out[2 * POSTK + pos] = (float)sg;
            }
        }
        __syncthreads();
        if (tid == 0) {
            unsigned inclLast = pref[valid - 1];
            bases[0] += inclLast;
            bases[1] += (unsigned)valid - inclLast;
        }
        __syncthreads();
    }
}

// ---------------------------------------------------------------------------
extern "C" void kernel_launch(void* const* d_in, const int* in_sizes, int n_in,
                              void* d_out, int out_size, void* d_ws, size_t ws_size,
                              hipStream_t stream)
{
    const float* rois = (const float*)d_in[0];
    const float* feat = (const float*)d_in[1];
    const float* W1s  = (const float*)d_in[2];
    const float* b1s  = (const float*)d_in[3];
    const float* W2s  = (const float*)d_in[4];
    const float* b2s  = (const float*)d_in[5];
    const float* W1o  = (const float*)d_in[6];
    const float* b1o  = (const float*)d_in[7];
    const float* W2o  = (const float*)d_in[8];
    const float* b2o  = (const float*)d_in[9];

    char* ws = (char*)d_ws;
    size_t off = 0;
    auto alloc = [&](size_t bytes) -> void* {
        off = (off + 255) & ~(size_t)255;
        void* p = ws + off;
        off += bytes;
        return p;
    };

    // zeroed region first
    unsigned* ghist = (unsigned*)alloc((size_t)BINS * 4);     // histogram
    unsigned* ctrl  = (unsigned*)alloc(256);                  // [0]=cand count, [1]=bin threshold
    unsigned* sup   = (unsigned*)alloc((size_t)6144 * 4);     // suppression flags
    unsigned* rank  = (unsigned*)alloc((size_t)CAP * 4);      // candidate ranks
    size_t zero_bytes = off;

    double* Xs64 = (double*)alloc((size_t)NB * HID * 8);
    double* Xo64 = (double*)alloc((size_t)NB * HID * 8);
    float*  XsT  = (float*)alloc((size_t)NB * HID * 4);
    float*  XoT  = (float*)alloc((size_t)NB * HID * 4);
    double* cval = (double*)alloc((size_t)CAP * 8);
    unsigned* cidx = (unsigned*)alloc((size_t)CAP * 4);
    double* svalv = (double*)alloc((size_t)TOPK * 8);
    unsigned* sidxv = (unsigned*)alloc((size_t)TOPK * 4);
    double* ub   = (double*)alloc((size_t)TOPK * 5 * 8);

    hipMemsetAsync(d_ws, 0, zero_bytes, stream);

    mlp_kernel<<<NB / 4, 256, 0, stream>>>(feat, W1s, b1s, W2s, b2s,
                                           W1o, b1o, W2o, b2o,
                                           Xs64, Xo64, XsT, XoT);
    scores_pass_a<<<dim3(64, 64), 256, 0, stream>>>(XsT, XoT, ghist);
    find_threshold<<<1, 256, 0, stream>>>(ghist, ctrl);
    scores_pass_b<<<dim3(64, 64), 256, 0, stream>>>(XsT, XoT, Xs64, Xo64, ctrl, cval, cidx);
    rank_count<<<dim3(CAP / 256, JSLICES), 256, 0, stream>>>(ctrl, cval, cidx, rank);
    rank_scatter<<<CAP / 256, 256, 0, stream>>>(ctrl, cval, cidx, rank, svalv, sidxv);
    nms_prep<<<(TOPK + 255) / 256, 256, 0, stream>>>(sidxv, rois, ub);
    nms_kernel<<<dim3((TOPK + 255) / 256, (TOPK + 255) / 256), 256, 0, stream>>>(ub, sup);
    finalize_kernel<<<1, 1024, 0, stream>>>(sup, svalv, sidxv, (float*)d_out);
}